// Round 16
// baseline (980.680 us; speedup 1.0000x reference)
//
#include <hip/hip_runtime.h>

#define BATCH 64
#define ATOMS 64
#define CIN 3
#define KS 8
#define H 224
#define W 224
#define OH 56
#define OW 56
#define NLAT (BATCH*ATOMS*OH*OW)   // 12,845,056
#define IMGSZ (OH*OW*ATOMS)        // 200,704 elems per image (channel-last)
#define LAM 0.1f
#define ETA 0.1f
// a-buffer: fp16, zero-padded halo, pre-swizzled: [img][R=0..57][C=0..57][64]
// element (R,C,n) at slot ((n>>3) ^ ((2R+C)&7))*8 + (n&7) within the 64.
// Per-image stride includes a 256-ushort (512 B) tail pad so the 44-chunk
// DMA overread of the last band stays in-bounds.
#define AROW 58
#define AIMG (AROW*AROW*64 + 256)  // 215,552 ushorts per image (padded)

typedef __attribute__((ext_vector_type(8)))  __bf16    bf16x8;
typedef __attribute__((ext_vector_type(8)))  _Float16  f16x8;
typedef __attribute__((ext_vector_type(16))) float     floatx16;

union FragU { uint4 u; bf16x8 v; };
union FragH { uint4 u; f16x8 v; };
union HalfBits { _Float16 h; unsigned short s; };

__device__ __forceinline__ float softthr(float u) {
    float p = u - LAM;  p = p > 0.f ? p : 0.f;
    float q = -u - LAM; q = q > 0.f ? q : 0.f;
    return p - q;
}
__device__ __forceinline__ unsigned short f2bf(float f) {   // RNE
    union { float f; unsigned int u; } c; c.f = f;
    unsigned int r = c.u + 0x7fffu + ((c.u >> 16) & 1u);
    return (unsigned short)(r >> 16);
}
__device__ __forceinline__ float bf2f(unsigned short h) {
    union { unsigned int u; float f; } c; c.u = ((unsigned int)h) << 16;
    return c.f;
}
__device__ __forceinline__ unsigned short f2h(float f) {    // fp16 bits, RNE
    HalfBits hb; hb.h = (_Float16)f; return hb.s;
}
__device__ __forceinline__ float h2f(unsigned short s) {
    HalfBits hb; hb.s = s; return (float)hb.h;
}
// swizzled ushort offset of atom n at padded coords (R,C) within an image
__device__ __forceinline__ size_t a_off(int img, int R, int C, int n) {
    return (size_t)img*AIMG + ((size_t)R*AROW + C)*64
         + ((((n >> 3) ^ ((2*R + C) & 7)) << 3) | (n & 7));
}

// Merged independent prep: blocks [0,1824) zero a-buffer halos,
// [1824,1872) build DT, [1872,1878) pack D (bf16 split).
__global__ void prep_a_kernel(const float* __restrict__ D,
                              unsigned short* __restrict__ A,
                              float* __restrict__ DT,
                              unsigned short* __restrict__ DAh,
                              unsigned short* __restrict__ DAl) {
    int bb = blockIdx.x;
    if (bb < 1824) {
        int idx = bb * 256 + threadIdx.x;   // 128 img-buf x 228 cells x 16 quads
        int ib = idx / 3648, r = idx % 3648;
        int cell = r >> 4, q = r & 15;
        int R, C;
        if      (cell < 58)  { R = 0;  C = cell; }
        else if (cell < 116) { R = 57; C = cell - 58; }
        else if (cell < 172) { R = cell - 116 + 1; C = 0; }
        else                 { R = cell - 172 + 1; C = 57; }
        size_t off = (size_t)ib*AIMG + ((size_t)R*AROW + C)*64 + q*4;
        *(ushort4*)(A + off) = make_ushort4(0, 0, 0, 0);
    } else if (bb < 1872) {
        int idx = (bb - 1824) * 256 + threadIdx.x;
        if (idx < CIN*KS*KS*ATOMS) {
            int m = idx & 63;
            int r = idx >> 6;
            int xk = r & 7, y = (r >> 3) & 7, c = r >> 6;
            DT[idx] = D[((m*CIN + c)*KS + y)*KS + xk];
        }
    } else {
        int g = (bb - 1872) * 256 + threadIdx.x;
        if (g >= 1536) return;
        int lane = g & 63;
        int r = g >> 6;
        int kstep = r % 12, mhalf = r / 12;
        int m = mhalf*32 + (lane & 31);
        int k0 = kstep*16 + (lane >> 5)*8;
#pragma unroll
        for (int j = 0; j < 8; ++j) {
            float v = D[m*192 + k0 + j];
            unsigned short h = f2bf(v);
            DAh[g*8 + j] = h;
            DAl[g*8 + j] = f2bf(v - bf2f(h));
        }
    }
}

// 9 table-sets (inclusion-exclusion for boundary classes), 9 dpq each.
__global__ void prep_gram_kernel(const float* __restrict__ DT,
                                 float* __restrict__ G) {
    int blk = blockIdx.x;              // td*16 + nchunk
    int td = blk >> 4;
    int tbl = td / 9, dpq = td % 9;
    int dp = dpq / 3, dq = dpq % 3;
    int di = 1 - dp, dj = 1 - dq;
    int ylo = (0 > -4*di) ? 0 : -4*di;
    int yhi = (8 < 8-4*di) ? 8 : 8-4*di;
    int xlo = (0 > -4*dj) ? 0 : -4*dj;
    int xhi = (8 < 8-4*dj) ? 8 : 8-4*dj;
    if (tbl==1 || tbl==5 || tbl==6) { if (yhi > 2) yhi = 2; }
    if (tbl==2 || tbl==7 || tbl==8) { if (ylo < 6) ylo = 6; }
    if (tbl==3 || tbl==5 || tbl==7) { if (xhi > 2) xhi = 2; }
    if (tbl==4 || tbl==6 || tbl==8) { if (xlo < 6) xlo = 6; }
    float sign = (tbl >= 1 && tbl <= 4) ? -1.f : 1.f;
    int t = threadIdx.x;
    int m = t & 63;
    int n = (blk & 15)*4 + (t >> 6);
    float s = 0.f;
    for (int c = 0; c < CIN; ++c)
        for (int y = ylo; y < yhi; ++y)
            for (int x = xlo; x < xhi; ++x)
                s += DT[((c*8+y)*8+x)*64 + m] *
                     DT[((c*8+y+4*di)*8 + (x+4*dj))*64 + n];
    G[td*4096 + n*64 + m] = sign * s;
}

// Pack G into MFMA A-operand layout, split FP16 hi/lo.
__global__ void prep_packg_kernel(const float* __restrict__ G,
                                  unsigned short* __restrict__ GAh,
                                  unsigned short* __restrict__ GAl) {
    int g = blockIdx.x * 256 + threadIdx.x;      // 162*256 = 41472 groups
    int lane = g & 63;
    int r = g >> 6;
    int kstep = r & 3; r >>= 2;
    int mhalf = r & 1; int td = r >> 1;          // tbl*9+dpq
    int m = mhalf*32 + (lane & 31);
    int n = kstep*16 + (lane >> 5)*8;
    const float* src = G + td*4096 + n*64 + m;
#pragma unroll
    for (int j = 0; j < 8; ++j) {
        float v = src[j*64];
        unsigned short h = f2h(v);
        GAh[g*8 + j] = h;
        GAl[g*8 + j] = f2h(v - h2f(h));
    }
}

// b = conv2d(x, D, stride4, pad2); u = 0.1*b; a1 = softthr(u) -> A0 (swizzled).
// Output CHANNEL-LAST [i][j][n].
__global__ __launch_bounds__(256) void conv_b_kernel(
        const float* __restrict__ x,
        const unsigned short* __restrict__ DAh,
        const unsigned short* __restrict__ DAl,
        float* __restrict__ b, float* __restrict__ u,
        unsigned short* __restrict__ A0) {
    __shared__ __align__(16) unsigned short xth[CIN*36*36];
    __shared__ __align__(16) unsigned short xtl[CIN*36*36];
    __shared__ float ot[64*65];
    int blk = blockIdx.x;
    int img = blk / 49, tile = blk % 49;
    int i0 = (tile / 7) * 8, j0 = (tile % 7) * 8;
    int t = threadIdx.x;
    int r0 = 4*i0 - 2, c0 = 4*j0 - 2;
    for (int f = t; f < CIN*36*36; f += 256) {
        int cc = f / 1296, rem = f % 1296;
        int rr = rem / 36, qq = rem % 36;
        int Y = r0 + rr, X = c0 + qq;
        float v = 0.f;
        if (Y >= 0 && Y < H && X >= 0 && X < W)
            v = x[((img*CIN + cc)*H + Y)*W + X];
        unsigned short h = f2bf(v);
        xth[f] = h;
        xtl[f] = f2bf(v - bf2f(h));
    }
    __syncthreads();
    int lane = t & 63, wave = t >> 6;
    int mhalf = wave & 1, poshalf = wave >> 1;
    int pos = poshalf*32 + (lane & 31), pi = pos >> 3, pj = pos & 7;
    int khalf = lane >> 5;
    floatx16 acc;
#pragma unroll
    for (int i = 0; i < 16; ++i) acc[i] = 0.f;
    const uint4* Ah4 = (const uint4*)DAh;
    const uint4* Al4 = (const uint4*)DAl;
#pragma unroll 3
    for (int kstep = 0; kstep < 12; ++kstep) {
        int k0 = kstep*16 + khalf*8;
        int cc = k0 >> 6, yy = (k0 >> 3) & 7;
        int boff = cc*1296 + (4*pi + yy)*36 + 4*pj;
        FragU ah, al, bh, bl;
        ah.u = Ah4[(mhalf*12 + kstep)*64 + lane];
        al.u = Al4[(mhalf*12 + kstep)*64 + lane];
        const uint2* ph = (const uint2*)(xth + boff);
        uint2 h0 = ph[0], h1 = ph[1];
        bh.u = make_uint4(h0.x, h0.y, h1.x, h1.y);
        const uint2* pl = (const uint2*)(xtl + boff);
        uint2 l0 = pl[0], l1 = pl[1];
        bl.u = make_uint4(l0.x, l0.y, l1.x, l1.y);
        acc = __builtin_amdgcn_mfma_f32_32x32x16_bf16(ah.v, bh.v, acc, 0, 0, 0);
        acc = __builtin_amdgcn_mfma_f32_32x32x16_bf16(ah.v, bl.v, acc, 0, 0, 0);
        acc = __builtin_amdgcn_mfma_f32_32x32x16_bf16(al.v, bh.v, acc, 0, 0, 0);
    }
#pragma unroll
    for (int r16 = 0; r16 < 16; ++r16) {
        int row = (r16 & 3) + 8*(r16 >> 2) + 4*khalf;
        ot[(mhalf*32 + row)*65 + pos] = acc[r16];
    }
    __syncthreads();
    // channel-last epilogue: lane = channel -> 256B contiguous stores
    int m = t & 63;
    float* bp = b + (size_t)img*IMGSZ;
    float* up = u + (size_t)img*IMGSZ;
#pragma unroll
    for (int e = 0; e < 16; ++e) {
        int pp = e*4 + (t >> 6);
        int gi = i0 + (pp >> 3), gj = j0 + (pp & 7);
        int gidx = (gi*OW + gj)*64 + m;
        float v = ot[m*65 + pp];
        bp[gidx] = v;
        float uv = ETA * v;
        up[gidx] = uv;
        A0[a_off(img, gi + 1, gj + 1, m)] = f2h(softthr(uv));
    }
}

// ---- MFMA helpers ----
__device__ __forceinline__ void load_a(uint4 (&A)[9], const uint4* __restrict__ Gh4,
                                       const uint4* __restrict__ Gl4,
                                       int txoff, int bb, int mhalf, int lane) {
    int dq = bb >> 2, ks = bb & 3;
#pragma unroll
    for (int dp = 0; dp < 3; ++dp) {
        int abase = (((3*dp + dq)*2 + mhalf)*4 + ks)*64 + lane;
        A[dp*3+0] = Gh4[abase];
        A[dp*3+1] = Gl4[abase];
        A[dp*3+2] = Gh4[txoff + abase];
    }
}
// 6 B-fragment slots (rows i0o..i0o+5 of the staged band) for one body.
__device__ __forceinline__ void load_b6(uint4 (&B)[6], const uint4* __restrict__ B4h,
                                        int bb, int khalf, int pjx) {
    int dq = bb >> 2, ks = bb & 3;
    int kg2 = ks*2 + khalf;
#pragma unroll
    for (int p = 0; p < 6; ++p) {
        int rc = p*58 + pjx + dq;
        B[p] = B4h[rc*8 + (kg2 ^ (rc & 7))];
    }
}
// Two row-pairs sharing the same A fragments: pair0 = rows (i0o, i0o+1)
// using slots dp, dp+1; pair1 = rows (i0o+2, i0o+3) using slots dp+2, dp+3.
__device__ __forceinline__ void do_mfma2(floatx16& a00, floatx16& a01,
                                         floatx16& a10, floatx16& a11,
                                         const uint4 (&A)[9], const uint4 (&B)[6],
                                         unsigned msel) {
    __builtin_amdgcn_s_setprio(1);
#pragma unroll
    for (int dp = 0; dp < 3; ++dp) {
        FragH a0, a1, ax;
        a0.u = A[dp*3+0]; a1.u = A[dp*3+1]; ax.u = A[dp*3+2];
        FragH b0, b1, bm0, bm1;
        b0.u = B[dp]; b1.u = B[dp+1];
        bm0.u = make_uint4(b0.u.x & msel, b0.u.y & msel,
                           b0.u.z & msel, b0.u.w & msel);
        bm1.u = make_uint4(b1.u.x & msel, b1.u.y & msel,
                           b1.u.z & msel, b1.u.w & msel);
        a00 = __builtin_amdgcn_mfma_f32_32x32x16_f16(a0.v, b0.v, a00, 0,0,0);
        a01 = __builtin_amdgcn_mfma_f32_32x32x16_f16(a0.v, b1.v, a01, 0,0,0);
        a00 = __builtin_amdgcn_mfma_f32_32x32x16_f16(a1.v, b0.v, a00, 0,0,0);
        a01 = __builtin_amdgcn_mfma_f32_32x32x16_f16(a1.v, b1.v, a01, 0,0,0);
        a00 = __builtin_amdgcn_mfma_f32_32x32x16_f16(ax.v, bm0.v, a00, 0,0,0);
        a01 = __builtin_amdgcn_mfma_f32_32x32x16_f16(ax.v, bm1.v, a01, 0,0,0);
        FragH c0, c1, cm0, cm1;
        c0.u = B[dp+2]; c1.u = B[dp+3];
        cm0.u = make_uint4(c0.u.x & msel, c0.u.y & msel,
                           c0.u.z & msel, c0.u.w & msel);
        cm1.u = make_uint4(c1.u.x & msel, c1.u.y & msel,
                           c1.u.z & msel, c1.u.w & msel);
        a10 = __builtin_amdgcn_mfma_f32_32x32x16_f16(a0.v, c0.v, a10, 0,0,0);
        a11 = __builtin_amdgcn_mfma_f32_32x32x16_f16(a0.v, c1.v, a11, 0,0,0);
        a10 = __builtin_amdgcn_mfma_f32_32x32x16_f16(a1.v, c0.v, a10, 0,0,0);
        a11 = __builtin_amdgcn_mfma_f32_32x32x16_f16(a1.v, c1.v, a11, 0,0,0);
        a10 = __builtin_amdgcn_mfma_f32_32x32x16_f16(ax.v, cm0.v, a10, 0,0,0);
        a11 = __builtin_amdgcn_mfma_f32_32x32x16_f16(ax.v, cm1.v, a11, 0,0,0);
    }
    __builtin_amdgcn_s_setprio(0);
}
// Y-boundary correction for ONE output row (the image-edge row): applies
// tby (hi+lo) and tbc (masked) terms on top of the interior result.
// Valid because staged halo rows are zero, so the interior path's T0/tbx
// application over them contributes nothing.
__device__ __forceinline__ void edge_corr(floatx16& tgt,
        const uint4* __restrict__ B4h, const uint4* __restrict__ Gh4,
        const uint4* __restrict__ Gl4, int slotbase, int pjx,
        int mhalf, int khalf, int lane, unsigned msel, int tby, int tbc) {
#pragma unroll 1
    for (int dq = 0; dq < 3; ++dq) {
#pragma unroll 1
        for (int ks = 0; ks < 4; ++ks) {
            int kg2 = ks*2 + khalf;
#pragma unroll
            for (int dp = 0; dp < 3; ++dp) {
                int rc = (slotbase + dp)*58 + pjx + dq;
                FragH B0, bm, ah, al, ac;
                B0.u = B4h[rc*8 + (kg2 ^ (rc & 7))];
                int ab = (((tby*9 + 3*dp + dq)*2 + mhalf)*4 + ks)*64 + lane;
                int cb = (((tbc*9 + 3*dp + dq)*2 + mhalf)*4 + ks)*64 + lane;
                ah.u = Gh4[ab];
                al.u = Gl4[ab];
                ac.u = Gh4[cb];
                bm.u = make_uint4(B0.u.x & msel, B0.u.y & msel,
                                  B0.u.z & msel, B0.u.w & msel);
                tgt = __builtin_amdgcn_mfma_f32_32x32x16_f16(ah.v, B0.v, tgt, 0,0,0);
                tgt = __builtin_amdgcn_mfma_f32_32x32x16_f16(al.v, B0.v, tgt, 0,0,0);
                tgt = __builtin_amdgcn_mfma_f32_32x32x16_f16(ac.v, bm.v, tgt, 0,0,0);
            }
        }
    }
}

// One LCA step on a 4-row x 56-col band, 256 threads = 4 waves {mhalf, cgrp}.
// R18 = R17 + T14 async-split epilogue prefetch: chunk-0's u/b float4 loads
// issue BEFORE the MFMA main loop (latency hides under ~6us of MFMA issue);
// chunk-1's issue right after MFMA, before the first barrier (hide under
// transpose + chunk-0 compute). Addresses are MFMA-independent; in-place u
// is only written by the owning block, so early reads are safe.
__global__ __launch_bounds__(256, 2) void lca_iter_kernel(
        const float* __restrict__ b, float* __restrict__ u,
        const unsigned short* __restrict__ Ain,
        unsigned short* __restrict__ Aout,
        const unsigned short* __restrict__ GAh,
        const unsigned short* __restrict__ GAl,
        float* __restrict__ out, int last) {
    __shared__ __align__(1024) unsigned char smem[45056];  // 44 KB stage / 29120 ot
    unsigned short* at2h = (unsigned short*)smem;          // [rc][swizzled n]
    int blk = blockIdx.x;
    int img = blk / 14, bandq = blk % 14;
    int i0o = bandq*4;                 // first output row of the band
    int t = threadIdx.x;
    // Phase 1: padded rows R = 4*bandq .. +5 (6 rows x 58 x 64 fp16) -> LDS.
    {
        const char* gbase = (const char*)(Ain + (size_t)img*AIMG
                              + (size_t)i0o*AROW*64) + (t & 63)*16;
        char* lbase = (char*)smem;
        int w = t >> 6;
        for (int c = w; c < 44; c += 4) {
            __builtin_amdgcn_global_load_lds(
                (const __attribute__((address_space(1))) unsigned int*)(gbase + c*1024),
                (__attribute__((address_space(3))) unsigned int*)(lbase + c*1024),
                16, 0, 0);
        }
    }
    const float* bp = b + (size_t)img*IMGSZ;
    float* up = u + (size_t)img*IMGSZ;          // in-place state update
    // T14 prefetch: chunk-0 (rows i0o, i0o+1) u/b inputs, MFMA-independent.
    float4 u0r[7], b0r[7];
#pragma unroll
    for (int p = 0; p < 7; ++p) {
        int qi = p*256 + t;                 // 0..1791
        int n0 = (qi & 15) * 4;
        int rest = qi >> 4;                 // 0..111
        int pi = (rest >= 56) ? 1 : 0;
        int j = rest - 56*pi;
        int g = ((i0o + pi)*OW + j)*64 + n0;
        u0r[p] = *(const float4*)(up + g);
        b0r[p] = *(const float4*)(bp + g);
    }
    __syncthreads();
    int lane = t & 63, wave = t >> 6;
    int mhalf = wave & 1, cgrp = wave >> 1;
    int khalf = lane >> 5, cl = lane & 31;
    int pj = cgrp*32 + cl;
    int pjx = (pj < 56) ? pj : 0;                // clamp invalid columns
    floatx16 a00, a01, a10, a11;
#pragma unroll
    for (int i = 0; i < 16; ++i) { a00[i]=0.f; a01[i]=0.f; a10[i]=0.f; a11[i]=0.f; }
    const uint4* Gh4 = (const uint4*)GAh;
    const uint4* Gl4 = (const uint4*)GAl;
    const uint4* B4h = (const uint4*)at2h;
    int tbx = (cgrp == 0) ? 3 : 4;               // X boundary table
    int txoff = (tbx*9)*512;
    unsigned msel = (cl == ((cgrp == 0) ? 0 : 23)) ? 0xFFFFFFFFu : 0u;
    // ---- uniform main path: A double-buffered, B single-buffered, 12 bodies ----
    {
        uint4 Aa[9], Ab[9], B[6];
        load_a(Aa, Gh4, Gl4, txoff, 0, mhalf, lane);
#pragma unroll 1
        for (int it2 = 0; it2 < 6; ++it2) {
            int bb = it2*2;
            load_a(Ab, Gh4, Gl4, txoff, bb+1, mhalf, lane);
            load_b6(B, B4h, bb, khalf, pjx);
            do_mfma2(a00, a01, a10, a11, Aa, B, msel);
            if (it2 < 5) {
                load_a(Aa, Gh4, Gl4, txoff, bb+2, mhalf, lane);
            }
            load_b6(B, B4h, bb+1, khalf, pjx);
            do_mfma2(a00, a01, a10, a11, Ab, B, msel);
        }
    }
    // ---- Y-boundary correction (bandq 0: row 0 -> a00; bandq 13: row 55 -> a11) ----
    if (bandq == 0) {
        int tbc = (cgrp == 0) ? 5 : 6;
        edge_corr(a00, B4h, Gh4, Gl4, 0, pjx, mhalf, khalf, lane, msel, 1, tbc);
    } else if (bandq == 13) {
        int tbc = (cgrp == 0) ? 7 : 8;
        edge_corr(a11, B4h, Gh4, Gl4, 3, pjx, mhalf, khalf, lane, msel, 2, tbc);
    }
    // T14 prefetch: chunk-1 (rows i0o+2, i0o+3) u/b inputs — issued before
    // the first epilogue barrier, consumed after chunk-0's compute.
    float4 u1r[7], b1r[7];
#pragma unroll
    for (int p = 0; p < 7; ++p) {
        int qi = p*256 + t;
        int n0 = (qi & 15) * 4;
        int rest = qi >> 4;
        int pi = (rest >= 56) ? 1 : 0;
        int j = rest - 56*pi;
        int g = ((i0o + 2 + pi)*OW + j)*64 + n0;
        u1r[p] = *(const float4*)(up + g);
        b1r[p] = *(const float4*)(bp + g);
    }
    // Epilogue: two 2-row chunks; at2h dead after first barrier.
    float* ot = (float*)smem;          // 112*65*4 = 29120 B
    // ---- chunk 0 ----
    __syncthreads();                   // MFMA reads of at2h done
    if (pj < 56) {
#pragma unroll
        for (int r16 = 0; r16 < 16; ++r16) {
            int row = (r16 & 3) + 8*(r16 >> 2) + 4*khalf;
            int m = mhalf*32 + row;
            ot[pj*65 + m] = a00[r16];
            ot[(56 + pj)*65 + m] = a01[r16];
        }
    }
    __syncthreads();
#pragma unroll
    for (int p = 0; p < 7; ++p) {
        int qi = p*256 + t;
        int n0 = (qi & 15) * 4;
        int rest = qi >> 4;
        int pi = (rest >= 56) ? 1 : 0;
        int j = rest - 56*pi;
        int iout = i0o + pi;
        int g = (iout*OW + j)*64 + n0;
        float4 uv = u0r[p], bv = b0r[p];
        const float* otr = ot + (pi*56 + j)*65 + n0;
        float u0 = uv.x + ETA*(bv.x - uv.x - otr[0] + softthr(uv.x));
        float u1 = uv.y + ETA*(bv.y - uv.y - otr[1] + softthr(uv.y));
        float u2 = uv.z + ETA*(bv.z - uv.z - otr[2] + softthr(uv.z));
        float u3 = uv.w + ETA*(bv.w - uv.w - otr[3] + softthr(uv.w));
        if (last) {
            size_t base = (((size_t)img*ATOMS + n0)*OH + iout)*OW + j;
            out[base]           = softthr(u0);
            out[base + OH*OW]   = softthr(u1);
            out[base + 2*OH*OW] = softthr(u2);
            out[base + 3*OH*OW] = softthr(u3);
        } else {
            *(float4*)(up + g) = make_float4(u0, u1, u2, u3);
            int R = iout + 1, C = j + 1;
            int key = (2*R + C) & 7;
            unsigned short* cell = Aout + (size_t)img*AIMG
                                 + ((size_t)R*AROW + C)*64;
            *(ushort4*)(cell + (((n0 >> 3) ^ key) << 3) + (n0 & 7)) =
                make_ushort4(f2h(softthr(u0)), f2h(softthr(u1)),
                             f2h(softthr(u2)), f2h(softthr(u3)));
        }
    }
    // ---- chunk 1 ----
    __syncthreads();                   // chunk-0 ot reads done
    if (pj < 56) {
#pragma unroll
        for (int r16 = 0; r16 < 16; ++r16) {
            int row = (r16 & 3) + 8*(r16 >> 2) + 4*khalf;
            int m = mhalf*32 + row;
            ot[pj*65 + m] = a10[r16];
            ot[(56 + pj)*65 + m] = a11[r16];
        }
    }
    __syncthreads();
#pragma unroll
    for (int p = 0; p < 7; ++p) {
        int qi = p*256 + t;
        int n0 = (qi & 15) * 4;
        int rest = qi >> 4;
        int pi = (rest >= 56) ? 1 : 0;
        int j = rest - 56*pi;
        int iout = i0o + 2 + pi;
        int g = (iout*OW + j)*64 + n0;
        float4 uv = u1r[p], bv = b1r[p];
        const float* otr = ot + (pi*56 + j)*65 + n0;
        float u0 = uv.x + ETA*(bv.x - uv.x - otr[0] + softthr(uv.x));
        float u1 = uv.y + ETA*(bv.y - uv.y - otr[1] + softthr(uv.y));
        float u2 = uv.z + ETA*(bv.z - uv.z - otr[2] + softthr(uv.z));
        float u3 = uv.w + ETA*(bv.w - uv.w - otr[3] + softthr(uv.w));
        if (last) {
            size_t base = (((size_t)img*ATOMS + n0)*OH + iout)*OW + j;
            out[base]           = softthr(u0);
            out[base + OH*OW]   = softthr(u1);
            out[base + 2*OH*OW] = softthr(u2);
            out[base + 3*OH*OW] = softthr(u3);
        } else {
            *(float4*)(up + g) = make_float4(u0, u1, u2, u3);
            int R = iout + 1, C = j + 1;
            int key = (2*R + C) & 7;
            unsigned short* cell = Aout + (size_t)img*AIMG
                                 + ((size_t)R*AROW + C)*64;
            *(ushort4*)(cell + (((n0 >> 3) ^ key) << 3) + (n0 & 7)) =
                make_ushort4(f2h(softthr(u0)), f2h(softthr(u1)),
                             f2h(softthr(u2)), f2h(softthr(u3)));
        }
    }
}

extern "C" void kernel_launch(void* const* d_in, const int* in_sizes, int n_in,
                              void* d_out, int out_size, void* d_ws, size_t ws_size,
                              hipStream_t stream) {
    const float* x = (const float*)d_in[0];
    const float* D = (const float*)d_in[1];
    float* out = (float*)d_out;
    float* ws = (float*)d_ws;
    float* b  = ws;                        // NLAT f32 (channel-last)
    float* u  = b  + NLAT;                 // NLAT f32 (single buffer, in-place)
    float* DT = u  + NLAT;                 // 12288 f32
    float* Gf = DT + 12288;                // 81*4096 f32
    unsigned short* GAh = (unsigned short*)(Gf + 331776);
    unsigned short* GAl = GAh + 331776;
    unsigned short* DAh = GAl + 331776;
    unsigned short* DAl = DAh + 12288;
    unsigned short* A0  = DAl + 12288;     // 64*215552 ushorts (padded stride)
    unsigned short* A1  = A0 + (size_t)BATCH*AIMG;
    prep_a_kernel<<<1878, 256, 0, stream>>>(D, A0, DT, DAh, DAl);
    prep_gram_kernel<<<1296, 256, 0, stream>>>(DT, Gf);
    prep_packg_kernel<<<162, 256, 0, stream>>>(Gf, GAh, GAl);
    conv_b_kernel<<<BATCH*49, 256, 0, stream>>>(x, DAh, DAl, b, u, A0);
    unsigned short* ain = A0; unsigned short* aout = A1;
    for (int it = 0; it < 9; ++it) {       // iterations 2..10 (iter 1 folded)
        int last = (it == 8);
        lca_iter_kernel<<<BATCH*14, 256, 0, stream>>>(b, u, ain, aout, GAh, GAl, out, last);
        unsigned short* tmp = ain; ain = aout; aout = tmp;
    }
}